// Round 9
// baseline (468.106 us; speedup 1.0000x reference)
//
#include <hip/hip_runtime.h>
#include <hip/hip_bf16.h>
#include <hip/hip_fp16.h>

// Decoder_22273700397282 on MI355X (gfx950)
// out[b,f] = trigger_a[b,f] * sum_t softmax_f(tanh(a@Wa + ba + s@Ws + bs))[t,f]
// mask==0 rows -> exactly 1/3072 per feature (handled analytically).
//
// R9: GEMM retiled BN 256->192: nact = 32 M-tiles x 16 N-tiles = 512 blocks
// = exactly 2 full rounds at 1 block/CU (kills the half-empty 2nd round that
// cost 25% of makespan). B-tile now [192][64] k-contiguous, 3x8KB granules,
// chunk-XOR c^(row&7) (2-way, free). 8-phase skeleton kept; slot schedule
// re-derived: vmcnt(3) at ph4/ph8 only, all stage->read leads >=3 phases,
// WAR separated by >=1 barrier. Dpart regrained to 48 cols (NDB=64).
// k_final1 -> half2 + LDS-staged invD.

namespace {
constexpr int SIN  = 1024;            // IN_SIZE
constexpr int KH   = 2048;            // 2*IN
constexpr int NF   = 3072;            // 3*IN = GEMM K and N
constexpr int NBAT = 32;
constexpr int NS   = 512;
constexpr int NM   = NBAT * NS;       // 16384 worst-case GEMM rows
constexpr int NDB  = 64;              // 48-col Dpart blocks (3072/48)
constexpr int KC   = 8;               // k-chunks for k_base1
constexpr int NKT  = NF / 64;         // 48 K-tiles of 64
constexpr int NCH  = 8;               // 64-row chunks per batch
}

typedef unsigned short u16;
typedef __bf16 bf16x8 __attribute__((ext_vector_type(8)));
typedef float  f32x4  __attribute__((ext_vector_type(4)));

#define ASYNC_CP16(gptr, lptr)                                                              \
  __builtin_amdgcn_global_load_lds((__attribute__((address_space(1))) void*)(gptr),         \
                                   (__attribute__((address_space(3))) void*)(lptr), 16, 0, 0)

__device__ __forceinline__ u16 f2b(float f) {
  union { float f; unsigned u; } v; v.f = f;
  unsigned u = v.u;
  u += 0x7FFFu + ((u >> 16) & 1u);     // round-to-nearest-even
  return (u16)(u >> 16);
}

// ---------------- compaction: counts ----------------
__global__ __launch_bounds__(64) void k_cnt(const int* __restrict__ mask,
                                            int* __restrict__ bcnt) {
  int b = blockIdx.x, t = threadIdx.x;
  int c = 0;
#pragma unroll
  for (int i = 0; i < NS / 64; ++i) c += mask[b * NS + i * 64 + t];
#pragma unroll
  for (int off = 32; off >= 1; off >>= 1) c += __shfl_down(c, off, 64);
  if (t == 0) bcnt[b] = c;
}

// ---------------- compaction: scan ----------------
__global__ __launch_bounds__(64) void k_scan(const int* __restrict__ bcnt,
                                             int* __restrict__ boff,
                                             int* __restrict__ meta) {
  if (threadIdx.x == 0) {
    int run = 0;
    for (int b = 0; b < NBAT; ++b) { boff[b] = run; run += bcnt[b]; }
    meta[0] = run;                       // Mc
    meta[1] = (run + 255) & ~255;        // McPad (256-row tiles)
  }
}

// ---------------- compaction: gather ----------------
__global__ __launch_bounds__(512) void k_gather(const int* __restrict__ mask,
                                                const int* __restrict__ boff,
                                                const int* __restrict__ meta,
                                                int* __restrict__ rowmap) {
  __shared__ int ps[NS];
  int b = blockIdx.x, t = threadIdx.x;
  int m = mask[b * NS + t];
  ps[t] = m;
  __syncthreads();
#pragma unroll
  for (int off = 1; off < NS; off <<= 1) {
    int v = (t >= off) ? ps[t - off] : 0;
    __syncthreads();
    ps[t] += v;
    __syncthreads();
  }
  if (m) rowmap[boff[b] + ps[t] - m] = b * NS + t;
  if (b == 0) {                          // zero-pad rowmap up to McPad
    int Mc = meta[0], McPad = meta[1];
    if (Mc + t < McPad) rowmap[Mc + t] = 0;
  }
}

// ---------------- s[b,k] = sum_t h[b,t,k] ----------------
__global__ __launch_bounds__(256) void k_sum_h(const float* __restrict__ h,
                                               float* __restrict__ s) {
  int b = blockIdx.x;
  int d = blockIdx.y * 256 + threadIdx.x;
  const float* p = h + (size_t)b * NS * KH + d;
  float acc = 0.f;
#pragma unroll 8
  for (int t = 0; t < NS; ++t) acc += p[(size_t)t * KH];
  s[b * KH + d] = acc;
}

// ---------------- base partials: reads Ws once ----------------
__global__ __launch_bounds__(256) void k_base1(const float* __restrict__ s,
                                               const float* __restrict__ Ws,
                                               float* __restrict__ basep) {
  __shared__ float sT[NBAT][KH / KC];      // [32][256] = 32 KB
  int f  = blockIdx.x * 256 + threadIdx.x;
  int k0 = blockIdx.y * (KH / KC);
  for (int it = 0; it < NBAT; ++it) {
    int idx = it * 256 + threadIdx.x;
    int b = idx >> 8, kk = idx & 255;
    sT[b][kk] = s[b * KH + k0 + kk];
  }
  __syncthreads();
  float acc[NBAT] = {};
  for (int k = 0; k < KH / KC; ++k) {
    float w = Ws[(size_t)(k0 + k) * NF + f];
#pragma unroll
    for (int b = 0; b < NBAT; ++b) acc[b] += sT[b][k] * w;
  }
#pragma unroll
  for (int b = 0; b < NBAT; ++b)
    basep[((size_t)blockIdx.y * NBAT + b) * NF + f] = acc[b];
}

__global__ __launch_bounds__(256) void k_base2(const float* __restrict__ basep,
                                               const float* __restrict__ ba,
                                               const float* __restrict__ bs,
                                               float* __restrict__ base) {
  int b = blockIdx.x;
  int f = blockIdx.y * 256 + threadIdx.x;
  float acc = 0.f;
#pragma unroll
  for (int kc = 0; kc < KC; ++kc) acc += basep[((size_t)kc * NBAT + b) * NF + f];
  base[b * NF + f] = acc + ba[f] + bs[f];
}

// ---------------- Abf[i,k] = bf16(concat(h,x)[rowmap[i],k]) ----------------
__global__ __launch_bounds__(256) void k_cvt_a(const float* __restrict__ h,
                                               const float* __restrict__ x,
                                               const int* __restrict__ rowmap,
                                               const int* __restrict__ meta,
                                               u16* __restrict__ A) {
  int tid = blockIdx.x * 256 + threadIdx.x;
  int i = tid / (NF / 4);
  if (i >= meta[1]) return;
  int k = (tid - i * (NF / 4)) * 4;
  ushort4 o;
  if (i >= meta[0]) {
    o.x = o.y = o.z = o.w = 0;
  } else {
    int ro = rowmap[i];
    int b = ro >> 9, t = ro & 511;
    const float* src = (k < KH) ? h + ((size_t)b * NS + t) * KH + k
                                : x + ((size_t)b * NS + t) * SIN + (k - KH);
    float4 v = *(const float4*)src;
    o.x = f2b(v.x); o.y = f2b(v.y); o.z = f2b(v.z); o.w = f2b(v.w);
  }
  *(ushort4*)(A + (size_t)i * NF + k) = o;
}

// ---------------- WaT[f,k] = bf16(Wa[k,f]) ----------------
__global__ __launch_bounds__(256) void k_wat(const float* __restrict__ Wa,
                                             u16* __restrict__ WaT) {
  __shared__ float tile[64][65];
  int k0 = blockIdx.x * 64, f0 = blockIdx.y * 64;
  int tid = threadIdx.x;
  int col4 = (tid & 15) * 4, row = tid >> 4;
#pragma unroll
  for (int rr = 0; rr < 64; rr += 16) {
    float4 v = *(const float4*)(Wa + (size_t)(k0 + row + rr) * NF + f0 + col4);
    tile[row + rr][col4 + 0] = v.x; tile[row + rr][col4 + 1] = v.y;
    tile[row + rr][col4 + 2] = v.z; tile[row + rr][col4 + 3] = v.w;
  }
  __syncthreads();
#pragma unroll
  for (int rr = 0; rr < 64; rr += 16) {
    int f = f0 + row + rr;
    ushort4 o;
    o.x = f2b(tile[col4 + 0][row + rr]); o.y = f2b(tile[col4 + 1][row + rr]);
    o.z = f2b(tile[col4 + 2][row + rr]); o.w = f2b(tile[col4 + 3][row + rr]);
    *(ushort4*)(WaT + (size_t)f * NF + k0 + col4) = o;
  }
}

// ---------------- main GEMM: 256x192 tile, 8-phase schedule ----------------
// ldsA[buf][ks][256x32 subtile], row*32 + chunk-XOR ((row>>1)&3) (2-way).
// ldsB[buf][192x64 rows k-contiguous], chunk-XOR c^(row&7) (2-way).
#define LDSOFF(row, gg) ((row) * 32 + ((((gg) ^ (((row) >> 1) & 3))) << 3))

#define LDB3(BUF, KS)                                                        \
  _Pragma("unroll") for (int nf = 0; nf < 3; ++nf) {                         \
    int rb = wc * 48 + nf * 16 + lr;                                         \
    bfr[nf] = *(const bf16x8*)                                               \
        &ldsB[BUF][rb * 64 + (((((KS) * 4) + g) ^ (rb & 7)) << 3)];          \
  }

#define LDA4(BUF, KS, MH)                                                    \
  _Pragma("unroll") for (int mf = 0; mf < 4; ++mf) {                         \
    int ra = wr * 128 + ((MH) * 4 + mf) * 16 + lr;                           \
    afr[mf] = *(const bf16x8*)&ldsA[BUF][KS][LDSOFF(ra, g)];                 \
  }

#define MFMA12(MH)                                                           \
  _Pragma("unroll") for (int mf = 0; mf < 4; ++mf)                           \
  _Pragma("unroll") for (int nf = 0; nf < 3; ++nf)                           \
    acc[(MH) * 4 + mf][nf] = __builtin_amdgcn_mfma_f32_16x16x32_bf16(        \
        afr[mf], bfr[nf], acc[(MH) * 4 + mf][nf], 0, 0, 0);

#define STAGE_A(SBUF, SKS, Q, SKT)                                           \
  if ((SKT) < NKT)                                                           \
    ASYNC_CP16(pA[Q] + (SKT) * 64 + (SKS) * 32,                              \
               &ldsA[SBUF][SKS][(Q) * 4096 + wid * 512]);

#define STAGE_B(SBUF, Q, SKT)                                                \
  if ((SKT) < NKT)                                                           \
    ASYNC_CP16(pBg[Q] + (SKT) * 64, &ldsB[SBUF][(Q) * 4096 + wid * 512]);

// one barrier per phase; vmcnt(3) only where VM=1 (ph4/ph8)
#define PH(BUF, KS, MH, VM, STAGES)                                          \
  {                                                                          \
    if ((MH) == 0) { LDB3(BUF, KS) }                                         \
    LDA4(BUF, KS, MH)                                                        \
    STAGES                                                                   \
    __builtin_amdgcn_s_setprio(1);                                           \
    MFMA12(MH)                                                               \
    __builtin_amdgcn_s_setprio(0);                                           \
    if (VM) asm volatile("s_waitcnt vmcnt(3)" ::: "memory");                 \
    __builtin_amdgcn_s_barrier();                                            \
  }

__global__ __launch_bounds__(512, 2) void k_gemm(const u16* __restrict__ A,
                                                 const u16* __restrict__ Wt,
                                                 const float* __restrict__ base,
                                                 const int* __restrict__ rowmap,
                                                 const int* __restrict__ meta,
                                                 __half* __restrict__ P,
                                                 float* __restrict__ Dpart) {
  __shared__ __align__(16) u16 ldsA[2][2][8192];     // 64 KB
  __shared__ __align__(16) u16 ldsB[2][12288];       // 48 KB
  const int MT   = meta[1] >> 8;                      // active M-tiles
  const int nact = MT * 16;                           // N-tiles = 3072/192
  const int flat = blockIdx.x;
  if (flat >= nact) return;
  const int qx = nact >> 3, rx = nact & 7;
  const int xcd = flat & 7, idx = flat >> 3;
  const int swz = (xcd < rx) ? xcd * (qx + 1) + idx
                             : rx * (qx + 1) + (xcd - rx) * qx + idx;
  const int mt = swz >> 4, nt = swz & 15;             // n fastest: A-panel reuse
  const int r0 = mt << 8, c0 = nt * 192;

  const int tid = threadIdx.x;
  const int wid = tid >> 6, lane = tid & 63;
  const int wr = wid >> 2, wc = wid & 3;              // 2M x 4N waves, 128x48
  const int g = lane >> 4, lr = lane & 15;

  // staging source pointers (swizzles folded into source columns)
  const u16* pA[2];
#pragma unroll
  for (int q = 0; q < 2; ++q) {
    int c = q * 512 + tid;
    int row = c >> 2;
    int kc8 = (((c & 3) ^ ((row >> 1) & 3)) << 3);
    pA[q] = A + (size_t)(r0 + row) * NF + kc8;
  }
  const u16* pBg[3];
#pragma unroll
  for (int q = 0; q < 3; ++q) {
    int row = q * 64 + (tid >> 3);
    int cz = (((tid & 7) ^ ((tid >> 3) & 7)) << 3);
    pBg[q] = Wt + (size_t)(c0 + row) * NF + cz;
  }

  f32x4 acc[8][3] = {};
  bf16x8 afr[4], bfr[3];

  // prologue: kt0 complete (7) + kt1 A-ks0 (2) + kt1 B q0 (1) = 10 issues
  STAGE_A(0, 0, 0, 0) STAGE_A(0, 0, 1, 0)
  STAGE_A(0, 1, 0, 0) STAGE_A(0, 1, 1, 0)
  STAGE_B(0, 0, 0)    STAGE_B(0, 1, 0)    STAGE_B(0, 2, 0)
  STAGE_A(1, 0, 0, 1) STAGE_A(1, 0, 1, 1)
  STAGE_B(1, 0, 1)
  asm volatile("s_waitcnt vmcnt(3)" ::: "memory");    // kt0's 7 landed
  __builtin_amdgcn_s_barrier();

  // main loop: tiles e=2i (buf0), o=2i+1 (buf1); kt2=2i+2, kt3=2i+3.
  // Stage slots (all leads >=3 phases; WAR >=1 barrier after last read):
  //  ph1: A1(o)x2   ph2: B(o)q1,q2   ph3: A0(kt2)x2  ph4: B(kt2)q0 +vm
  //  ph5: B(kt2)q1 + A1(kt2)q0       ph6: B(kt2)q2 + A1(kt2)q1
  //  ph7: A0(kt3)x2                  ph8: B(kt3)q0 +vm
#pragma unroll 1
  for (int i = 0; i < NKT / 2; ++i) {
    const int kto = 2 * i + 1, kt2 = 2 * i + 2, kt3 = 2 * i + 3;
    PH(0, 0, 0, 0, STAGE_A(1, 1, 0, kto) STAGE_A(1, 1, 1, kto))
    PH(0, 0, 1, 0, STAGE_B(1, 1, kto)    STAGE_B(1, 2, kto))
    PH(0, 1, 0, 0, STAGE_A(0, 0, 0, kt2) STAGE_A(0, 0, 1, kt2))
    PH(0, 1, 1, 1, STAGE_B(0, 0, kt2))
    PH(1, 0, 0, 0, STAGE_B(0, 1, kt2)    STAGE_A(0, 1, 0, kt2))
    PH(1, 0, 1, 0, STAGE_B(0, 2, kt2)    STAGE_A(0, 1, 1, kt2))
    PH(1, 1, 0, 0, STAGE_A(1, 0, 0, kt3) STAGE_A(1, 0, 1, kt3))
    PH(1, 1, 1, 1, STAGE_B(1, 0, kt3))
  }

  // epilogue: z = acc + base; P = exp(tanh(z)); Dpart 48-col rowsums
  const int cbase = c0 + wc * 48;
  const int dcol  = nt * 4 + wc;
#pragma unroll
  for (int mf = 0; mf < 8; ++mf) {
#pragma unroll
    for (int j = 0; j < 4; ++j) {
      int i = r0 + wr * 128 + mf * 16 + g * 4 + j;
      int b = rowmap[i] >> 9;
      float rs = 0.f;
#pragma unroll
      for (int nf = 0; nf < 3; ++nf) {
        int ccn = cbase + nf * 16 + lr;
        float z  = acc[mf][nf][j] + base[b * NF + ccn];
        z        = fminf(fmaxf(z, -15.f), 15.f);
        float e2 = __expf(2.f * z);
        float th = (e2 - 1.f) / (e2 + 1.f);
        float p  = __expf(th);
        P[(size_t)i * NF + ccn] = __float2half(p);
        rs += p;
      }
#pragma unroll
      for (int off = 1; off < 16; off <<= 1) rs += __shfl_xor(rs, off, 64);
      if (lr == 0) Dpart[(size_t)i * NDB + dcol] = rs;
    }
  }
}

// ---------------- invD[i] = 1 / sum_nb Dpart[i,nb] ----------------
__global__ __launch_bounds__(256) void k_invd(const float* __restrict__ Dpart,
                                              const int* __restrict__ meta,
                                              float* __restrict__ invD) {
  int i = blockIdx.x * 256 + threadIdx.x;
  if (i >= meta[1]) return;
  float d = 0.f;
#pragma unroll
  for (int q = 0; q < NDB; ++q) d += Dpart[(size_t)i * NDB + q];
  invD[i] = 1.0f / d;
}

// ---------------- final pass 1: per-(batch,chunk) partial sums ----------
__global__ __launch_bounds__(256) void k_final1(const __half* __restrict__ P,
                                                const float* __restrict__ invD,
                                                const int* __restrict__ boff,
                                                const int* __restrict__ bcnt,
                                                float* __restrict__ pb) {
  int c = blockIdx.x;                                // b*NCH + j
  int b = c >> 3, j = c & 7;
  int f = blockIdx.y * 512 + threadIdx.x * 2;
  int cnt = bcnt[b];
  int lo = j * 64, hi = min(cnt, lo + 64);
  int off = boff[b];
  __shared__ float ivs[64];
  if (threadIdx.x < 64 && lo + (int)threadIdx.x < hi)
    ivs[threadIdx.x] = invD[off + lo + threadIdx.x];
  __syncthreads();
  float ax = 0.f, ay = 0.f;
  for (int t = lo; t < hi; ++t) {
    __half2 hv = *(const __half2*)(P + (size_t)(off + t) * NF + f);
    float2 fv = __half22float2(hv);
    float iv = ivs[t - lo];
    ax += fv.x * iv; ay += fv.y * iv;
  }
  float2 o; o.x = ax; o.y = ay;
  *(float2*)(pb + (size_t)c * NF + f) = o;
}

// ---------------- final pass 2: combine + uniform + trigger mult ---------
__global__ __launch_bounds__(256) void k_final2(const float* __restrict__ pb,
                                                const int* __restrict__ bcnt,
                                                const float* __restrict__ h,
                                                const float* __restrict__ x,
                                                const int* __restrict__ trig,
                                                float* __restrict__ out) {
  int b = blockIdx.x;
  int f = blockIdx.y * 256 + threadIdx.x;
  float acc = 0.f;
#pragma unroll
  for (int j = 0; j < NCH; ++j) acc += pb[(size_t)(b * NCH + j) * NF + f];
  acc += (float)(NS - bcnt[b]) * (1.0f / (float)NF);
  int tr = trig[b];
  float ta = (f < KH) ? h[((size_t)b * NS + tr) * KH + f]
                      : x[((size_t)b * NS + tr) * SIN + f - KH];
  out[b * NF + f] = acc * ta;
}

extern "C" void kernel_launch(void* const* d_in, const int* in_sizes, int n_in,
                              void* d_out, int out_size, void* d_ws, size_t ws_size,
                              hipStream_t stream) {
  const float* h_state = (const float*)d_in[0];
  const float* x       = (const float*)d_in[1];
  const int*   trigger = (const int*)d_in[2];
  const int*   mask    = (const int*)d_in[3];
  const float* Wa      = (const float*)d_in[4];
  const float* ba      = (const float*)d_in[5];
  const float* Ws      = (const float*)d_in[6];
  const float* bs      = (const float*)d_in[7];
  float*       out     = (float*)d_out;

  // workspace layout (bytes), total ~225 MB
  char* w = (char*)d_ws;
  u16*    Abf   = (u16*)w;                 w += (size_t)NM * NF * 2;
  u16*    WaT   = (u16*)w;                 w += (size_t)NF * NF * 2;
  __half* P     = (__half*)w;              w += (size_t)NM * NF * 2;
  float*  s     = (float*)w;               w += (size_t)NBAT * KH * 4;
  float*  base  = (float*)w;               w += (size_t)NBAT * NF * 4;
  float*  Dpart = (float*)w;               w += (size_t)NM * NDB * 4;   // 4 MB
  float*  basep = (float*)Dpart;           // alias (read before k_gemm writes)
  float*  pb    = (float*)Dpart;           // alias (written after k_invd reads)
  float*  invD  = (float*)w;               w += (size_t)NM * 4;
  int*    rowmap= (int*)w;                 w += (size_t)NM * 4;
  int*    bcnt  = (int*)w;                 w += 128;
  int*    boff  = (int*)w;                 w += 128;
  int*    meta  = (int*)w;                 w += 128;

  (void)in_sizes; (void)n_in; (void)out_size; (void)ws_size;

  k_cnt   <<<dim3(NBAT), 64, 0, stream>>>(mask, bcnt);
  k_scan  <<<dim3(1), 64, 0, stream>>>(bcnt, boff, meta);
  k_gather<<<dim3(NBAT), 512, 0, stream>>>(mask, boff, meta, rowmap);
  k_sum_h <<<dim3(NBAT, KH / 256), 256, 0, stream>>>(h_state, s);
  k_cvt_a <<<dim3(NM * (NF / 4) / 256), 256, 0, stream>>>(h_state, x, rowmap, meta, Abf);
  k_wat   <<<dim3(NF / 64, NF / 64), 256, 0, stream>>>(Wa, WaT);
  k_base1 <<<dim3(NF / 256, KC), 256, 0, stream>>>(s, Ws, basep);
  k_base2 <<<dim3(NBAT, NF / 256), 256, 0, stream>>>(basep, ba, bs, base);
  k_gemm  <<<dim3((NF / 192) * (NM / 256)), 512, 0, stream>>>(Abf, WaT, base, rowmap, meta, P, Dpart);
  k_invd  <<<dim3(NM / 256), 256, 0, stream>>>(Dpart, meta, invD);
  k_final1<<<dim3(NBAT * NCH, NF / 512), 256, 0, stream>>>(P, invD, boff, bcnt, pb);
  k_final2<<<dim3(NBAT, NF / 256), 256, 0, stream>>>(pb, bcnt, h_state, x, trigger, out);
}

// Round 10
// 398.997 us; speedup vs baseline: 1.1732x; 1.1732x over previous
//
#include <hip/hip_runtime.h>
#include <hip/hip_bf16.h>
#include <hip/hip_fp16.h>

// Decoder_22273700397282 on MI355X (gfx950)
// out[b,f] = trigger_a[b,f] * sum_t softmax_f(tanh(a@Wa + ba + s@Ws + bs))[t,f]
// mask==0 rows -> exactly 1/3072 per feature (handled analytically).
//
// R10: consolidation. k_gemm reverted to the R8 state (256x256, 8-phase,
// no mid-phase barrier, uniform vmcnt(6), best measured: 200us/35% MfmaUtil).
// R9's BN=192 retile regressed (premature vmcnt drain + worse per-phase
// amortization) and is abandoned. Non-GEMM: k_cnt+k_scan merged into k_prep;
// k_cvt_a grid-stride (kills ~24K empty-block dispatches); k_final1 uses
// half2 loads + LDS-staged invD (validated in R9).

namespace {
constexpr int SIN  = 1024;            // IN_SIZE
constexpr int KH   = 2048;            // 2*IN
constexpr int NF   = 3072;            // 3*IN = GEMM K and N
constexpr int NBAT = 32;
constexpr int NS   = 512;
constexpr int NM   = NBAT * NS;       // 16384 worst-case GEMM rows
constexpr int NDB  = NF / 64;         // 48 Dpart column blocks
constexpr int KC   = 8;               // k-chunks for k_base1
constexpr int NKT  = NF / 64;         // 48 K-tiles of 64
constexpr int NCH  = 8;               // 64-row chunks per batch
}

typedef unsigned short u16;
typedef __bf16 bf16x8 __attribute__((ext_vector_type(8)));
typedef float  f32x4  __attribute__((ext_vector_type(4)));

#define ASYNC_CP16(gptr, lptr)                                                              \
  __builtin_amdgcn_global_load_lds((__attribute__((address_space(1))) void*)(gptr),         \
                                   (__attribute__((address_space(3))) void*)(lptr), 16, 0, 0)

__device__ __forceinline__ u16 f2b(float f) {
  union { float f; unsigned u; } v; v.f = f;
  unsigned u = v.u;
  u += 0x7FFFu + ((u >> 16) & 1u);     // round-to-nearest-even
  return (u16)(u >> 16);
}

// ---------------- prep: per-batch counts + scan + meta (one block) -------
__global__ __launch_bounds__(256) void k_prep(const int* __restrict__ mask,
                                              int* __restrict__ bcnt,
                                              int* __restrict__ boff,
                                              int* __restrict__ meta) {
  int tid = threadIdx.x;
  int b = tid >> 3, seg = tid & 7;                 // 8 threads per batch
  int c = 0;
#pragma unroll
  for (int i = 0; i < 64; ++i) c += mask[b * NS + seg * 64 + i];
  c += __shfl_xor(c, 1, 64);
  c += __shfl_xor(c, 2, 64);
  c += __shfl_xor(c, 4, 64);                       // 8-lane group total
  __shared__ int sc[NBAT];
  if (seg == 0) { sc[b] = c; bcnt[b] = c; }
  __syncthreads();
  if (tid == 0) {
    int run = 0;
    for (int bb = 0; bb < NBAT; ++bb) { boff[bb] = run; run += sc[bb]; }
    meta[0] = run;                       // Mc
    meta[1] = (run + 255) & ~255;        // McPad (256-row tiles)
  }
}

// ---------------- compaction: gather ----------------
__global__ __launch_bounds__(512) void k_gather(const int* __restrict__ mask,
                                                const int* __restrict__ boff,
                                                const int* __restrict__ meta,
                                                int* __restrict__ rowmap) {
  __shared__ int ps[NS];
  int b = blockIdx.x, t = threadIdx.x;
  int m = mask[b * NS + t];
  ps[t] = m;
  __syncthreads();
#pragma unroll
  for (int off = 1; off < NS; off <<= 1) {
    int v = (t >= off) ? ps[t - off] : 0;
    __syncthreads();
    ps[t] += v;
    __syncthreads();
  }
  if (m) rowmap[boff[b] + ps[t] - m] = b * NS + t;
  if (b == 0) {                          // zero-pad rowmap up to McPad
    int Mc = meta[0], McPad = meta[1];
    if (Mc + t < McPad) rowmap[Mc + t] = 0;
  }
}

// ---------------- s[b,k] = sum_t h[b,t,k] ----------------
__global__ __launch_bounds__(256) void k_sum_h(const float* __restrict__ h,
                                               float* __restrict__ s) {
  int b = blockIdx.x;
  int d = blockIdx.y * 256 + threadIdx.x;
  const float* p = h + (size_t)b * NS * KH + d;
  float acc = 0.f;
#pragma unroll 8
  for (int t = 0; t < NS; ++t) acc += p[(size_t)t * KH];
  s[b * KH + d] = acc;
}

// ---------------- base partials: reads Ws once ----------------
__global__ __launch_bounds__(256) void k_base1(const float* __restrict__ s,
                                               const float* __restrict__ Ws,
                                               float* __restrict__ basep) {
  __shared__ float sT[NBAT][KH / KC];      // [32][256] = 32 KB
  int f  = blockIdx.x * 256 + threadIdx.x;
  int k0 = blockIdx.y * (KH / KC);
  for (int it = 0; it < NBAT; ++it) {
    int idx = it * 256 + threadIdx.x;
    int b = idx >> 8, kk = idx & 255;
    sT[b][kk] = s[b * KH + k0 + kk];
  }
  __syncthreads();
  float acc[NBAT] = {};
  for (int k = 0; k < KH / KC; ++k) {
    float w = Ws[(size_t)(k0 + k) * NF + f];
#pragma unroll
    for (int b = 0; b < NBAT; ++b) acc[b] += sT[b][k] * w;
  }
#pragma unroll
  for (int b = 0; b < NBAT; ++b)
    basep[((size_t)blockIdx.y * NBAT + b) * NF + f] = acc[b];
}

__global__ __launch_bounds__(256) void k_base2(const float* __restrict__ basep,
                                               const float* __restrict__ ba,
                                               const float* __restrict__ bs,
                                               float* __restrict__ base) {
  int b = blockIdx.x;
  int f = blockIdx.y * 256 + threadIdx.x;
  float acc = 0.f;
#pragma unroll
  for (int kc = 0; kc < KC; ++kc) acc += basep[((size_t)kc * NBAT + b) * NF + f];
  base[b * NF + f] = acc + ba[f] + bs[f];
}

// ---------------- Abf[i,k] = bf16(concat(h,x)[rowmap[i],k]) --------------
// grid-stride over meta[1]*768 items (4 cols each) — no empty-block waste.
__global__ __launch_bounds__(256) void k_cvt_a(const float* __restrict__ h,
                                               const float* __restrict__ x,
                                               const int* __restrict__ rowmap,
                                               const int* __restrict__ meta,
                                               u16* __restrict__ A) {
  const int total = meta[1] * (NF / 4);
  for (int idx = blockIdx.x * 256 + threadIdx.x; idx < total;
       idx += gridDim.x * 256) {
    int i = idx / (NF / 4);
    int k = (idx - i * (NF / 4)) * 4;
    ushort4 o;
    if (i >= meta[0]) {
      o.x = o.y = o.z = o.w = 0;
    } else {
      int ro = rowmap[i];
      int b = ro >> 9, t = ro & 511;
      const float* src = (k < KH) ? h + ((size_t)b * NS + t) * KH + k
                                  : x + ((size_t)b * NS + t) * SIN + (k - KH);
      float4 v = *(const float4*)src;
      o.x = f2b(v.x); o.y = f2b(v.y); o.z = f2b(v.z); o.w = f2b(v.w);
    }
    *(ushort4*)(A + (size_t)i * NF + k) = o;
  }
}

// ---------------- WaT[f,k] = bf16(Wa[k,f]) ----------------
__global__ __launch_bounds__(256) void k_wat(const float* __restrict__ Wa,
                                             u16* __restrict__ WaT) {
  __shared__ float tile[64][65];
  int k0 = blockIdx.x * 64, f0 = blockIdx.y * 64;
  int tid = threadIdx.x;
  int col4 = (tid & 15) * 4, row = tid >> 4;
#pragma unroll
  for (int rr = 0; rr < 64; rr += 16) {
    float4 v = *(const float4*)(Wa + (size_t)(k0 + row + rr) * NF + f0 + col4);
    tile[row + rr][col4 + 0] = v.x; tile[row + rr][col4 + 1] = v.y;
    tile[row + rr][col4 + 2] = v.z; tile[row + rr][col4 + 3] = v.w;
  }
  __syncthreads();
#pragma unroll
  for (int rr = 0; rr < 64; rr += 16) {
    int f = f0 + row + rr;
    ushort4 o;
    o.x = f2b(tile[col4 + 0][row + rr]); o.y = f2b(tile[col4 + 1][row + rr]);
    o.z = f2b(tile[col4 + 2][row + rr]); o.w = f2b(tile[col4 + 3][row + rr]);
    *(ushort4*)(WaT + (size_t)f * NF + k0 + col4) = o;
  }
}

// ---------------- main GEMM: 256x256 tile, 8-phase, 1 barrier/phase -------
// (R8 state: best measured 200us, MfmaUtil 35%, bank conflicts 0.)
#define LDSOFF(row, gg) ((row) * 32 + ((((gg) ^ (((row) >> 1) & 3))) << 3))

#define LDB4(BUF, KS)                                                        \
  _Pragma("unroll") for (int nf = 0; nf < 4; ++nf) {                         \
    int rb = wc * 64 + nf * 16 + lr;                                         \
    bfr[nf] = *(const bf16x8*)&lds[BUF][1][KS][LDSOFF(rb, g)];               \
  }

#define LDA4(BUF, KS, MH)                                                    \
  _Pragma("unroll") for (int mf = 0; mf < 4; ++mf) {                         \
    int ra = wr * 128 + ((MH) * 4 + mf) * 16 + lr;                           \
    afr[mf] = *(const bf16x8*)&lds[BUF][0][KS][LDSOFF(ra, g)];               \
  }

#define MFMA16(MH)                                                           \
  _Pragma("unroll") for (int mf = 0; mf < 4; ++mf)                           \
  _Pragma("unroll") for (int nf = 0; nf < 4; ++nf)                           \
    acc[(MH) * 4 + mf][nf] = __builtin_amdgcn_mfma_f32_16x16x32_bf16(        \
        afr[mf], bfr[nf], acc[(MH) * 4 + mf][nf], 0, 0, 0);

#define STAGE(SMAT, SBUF, SKS, SKT)                                          \
  if ((SKT) < NKT) {                                                         \
    _Pragma("unroll") for (int q = 0; q < 2; ++q) {                          \
      const u16* src = ((SMAT) ? pB[q] : pA[q]) + (SKT) * 64 + (SKS) * 32;   \
      ASYNC_CP16(src, &lds[SBUF][SMAT][SKS][q * 4096 + wid * 512]);          \
    }                                                                        \
  }

#define PH(BUF, KS, MH, SMAT, SBUF, SKS, SKT)                                \
  {                                                                          \
    if ((MH) == 0) { LDB4(BUF, KS) }                                         \
    LDA4(BUF, KS, MH)                                                        \
    STAGE(SMAT, SBUF, SKS, SKT)                                              \
    __builtin_amdgcn_s_setprio(1);                                           \
    MFMA16(MH)                                                               \
    __builtin_amdgcn_s_setprio(0);                                           \
    asm volatile("s_waitcnt vmcnt(6)" ::: "memory");                         \
    __builtin_amdgcn_s_barrier();                                            \
  }

__global__ __launch_bounds__(512, 2) void k_gemm(const u16* __restrict__ A,
                                                 const u16* __restrict__ Wt,
                                                 const float* __restrict__ base,
                                                 const int* __restrict__ rowmap,
                                                 const int* __restrict__ meta,
                                                 __half* __restrict__ P,
                                                 float* __restrict__ Dpart) {
  __shared__ __align__(16) u16 lds[2][2][2][8192];   // 128 KB
  const int MT   = meta[1] >> 8;
  const int nact = MT * 12;
  const int flat = blockIdx.x;
  if (flat >= nact) return;
  const int qx = nact >> 3, rx = nact & 7;
  const int xcd = flat & 7, idx = flat >> 3;
  const int swz = (xcd < rx) ? xcd * (qx + 1) + idx
                             : rx * (qx + 1) + (xcd - rx) * qx + idx;
  const int mt = swz / 12, nt = swz - mt * 12;
  const int r0 = mt << 8, c0 = nt << 8;

  const int tid = threadIdx.x;
  const int wid = tid >> 6, lane = tid & 63;
  const int wr = wid >> 2, wc = wid & 3;
  const int g = lane >> 4, lr = lane & 15;

  const u16* pA[2]; const u16* pB[2];
#pragma unroll
  for (int q = 0; q < 2; ++q) {
    int c = q * 512 + tid;
    int row = c >> 2;
    int kc8 = (((c & 3) ^ ((row >> 1) & 3)) << 3);
    pA[q] = A  + (size_t)(r0 + row) * NF + kc8;
    pB[q] = Wt + (size_t)(c0 + row) * NF + kc8;
  }

  f32x4 acc[8][4] = {};
  bf16x8 afr[4], bfr[4];

  // prologue: kt0 complete + kt1 K-half0 (12 loads)
  STAGE(0, 0, 0, 0) STAGE(1, 0, 0, 0)
  STAGE(0, 0, 1, 0) STAGE(1, 0, 1, 0)
  STAGE(0, 1, 0, 1) STAGE(1, 1, 0, 1)
  asm volatile("s_waitcnt vmcnt(8)" ::: "memory");
  __builtin_amdgcn_s_barrier();

  // 8 phases / 2 K-tiles; stage slots have a 6-phase stage->read lead.
#pragma unroll 1
  for (int i = 0; i < NKT / 2; ++i) {
    const int kt1 = 2 * i + 1, kt2 = 2 * i + 2, kt3 = 2 * i + 3;
    PH(0, 0, 0, 0, 1, 1, kt1)
    PH(0, 0, 1, 1, 1, 1, kt1)
    PH(0, 1, 0, 0, 0, 0, kt2)
    PH(0, 1, 1, 1, 0, 0, kt2)
    PH(1, 0, 0, 0, 0, 1, kt2)
    PH(1, 0, 1, 1, 0, 1, kt2)
    PH(1, 1, 0, 0, 1, 0, kt3)
    PH(1, 1, 1, 1, 1, 0, kt3)
  }

  // epilogue: z = acc + base; P = exp(tanh(z)); Dpart rowsums
  const int cbase = c0 + wc * 64;
#pragma unroll
  for (int mf = 0; mf < 8; ++mf) {
#pragma unroll
    for (int j = 0; j < 4; ++j) {
      int i = r0 + wr * 128 + mf * 16 + g * 4 + j;
      int b = rowmap[i] >> 9;
      float rs = 0.f;
#pragma unroll
      for (int nf = 0; nf < 4; ++nf) {
        int ccn = cbase + nf * 16 + lr;
        float z  = acc[mf][nf][j] + base[b * NF + ccn];
        z        = fminf(fmaxf(z, -15.f), 15.f);
        float e2 = __expf(2.f * z);
        float th = (e2 - 1.f) / (e2 + 1.f);
        float p  = __expf(th);
        P[(size_t)i * NF + ccn] = __float2half(p);
        rs += p;
      }
#pragma unroll
      for (int off = 1; off < 16; off <<= 1) rs += __shfl_xor(rs, off, 64);
      if (lr == 0) Dpart[(size_t)i * NDB + (cbase >> 6)] = rs;
    }
  }
}

// ---------------- invD[i] = 1 / sum_nb Dpart[i,nb] ----------------
__global__ __launch_bounds__(256) void k_invd(const float* __restrict__ Dpart,
                                              const int* __restrict__ meta,
                                              float* __restrict__ invD) {
  int i = blockIdx.x * 256 + threadIdx.x;
  if (i >= meta[1]) return;
  float d = 0.f;
#pragma unroll
  for (int q = 0; q < NDB; ++q) d += Dpart[(size_t)i * NDB + q];
  invD[i] = 1.0f / d;
}

// ---------------- final pass 1: per-(batch,chunk) partial sums ----------
__global__ __launch_bounds__(256) void k_final1(const __half* __restrict__ P,
                                                const float* __restrict__ invD,
                                                const int* __restrict__ boff,
                                                const int* __restrict__ bcnt,
                                                float* __restrict__ pb) {
  int c = blockIdx.x;                                // b*NCH + j
  int b = c >> 3, j = c & 7;
  int f = blockIdx.y * 512 + threadIdx.x * 2;
  int cnt = bcnt[b];
  int lo = j * 64, hi = min(cnt, lo + 64);
  int off = boff[b];
  __shared__ float ivs[64];
  if (threadIdx.x < 64 && lo + (int)threadIdx.x < hi)
    ivs[threadIdx.x] = invD[off + lo + threadIdx.x];
  __syncthreads();
  float ax = 0.f, ay = 0.f;
  for (int t = lo; t < hi; ++t) {
    __half2 hv = *(const __half2*)(P + (size_t)(off + t) * NF + f);
    float2 fv = __half22float2(hv);
    float iv = ivs[t - lo];
    ax += fv.x * iv; ay += fv.y * iv;
  }
  float2 o; o.x = ax; o.y = ay;
  *(float2*)(pb + (size_t)c * NF + f) = o;
}

// ---------------- final pass 2: combine + uniform + trigger mult ---------
__global__ __launch_bounds__(256) void k_final2(const float* __restrict__ pb,
                                                const int* __restrict__ bcnt,
                                                const float* __restrict__ h,
                                                const float* __restrict__ x,
                                                const int* __restrict__ trig,
                                                float* __restrict__ out) {
  int b = blockIdx.x;
  int f = blockIdx.y * 256 + threadIdx.x;
  float acc = 0.f;
#pragma unroll
  for (int j = 0; j < NCH; ++j) acc += pb[(size_t)(b * NCH + j) * NF + f];
  acc += (float)(NS - bcnt[b]) * (1.0f / (float)NF);
  int tr = trig[b];
  float ta = (f < KH) ? h[((size_t)b * NS + tr) * KH + f]
                      : x[((size_t)b * NS + tr) * SIN + f - KH];
  out[b * NF + f] = acc * ta;
}

extern "C" void kernel_launch(void* const* d_in, const int* in_sizes, int n_in,
                              void* d_out, int out_size, void* d_ws, size_t ws_size,
                              hipStream_t stream) {
  const float* h_state = (const float*)d_in[0];
  const float* x       = (const float*)d_in[1];
  const int*   trigger = (const int*)d_in[2];
  const int*   mask    = (const int*)d_in[3];
  const float* Wa      = (const float*)d_in[4];
  const float* ba      = (const float*)d_in[5];
  const float* Ws      = (const float*)d_in[6];
  const float* bs      = (const float*)d_in[7];
  float*       out     = (float*)d_out;

  // workspace layout (bytes), total ~224 MB
  char* w = (char*)d_ws;
  u16*    Abf   = (u16*)w;                 w += (size_t)NM * NF * 2;
  u16*    WaT   = (u16*)w;                 w += (size_t)NF * NF * 2;
  __half* P     = (__half*)w;              w += (size_t)NM * NF * 2;
  float*  s     = (float*)w;               w += (size_t)NBAT * KH * 4;
  float*  base  = (float*)w;               w += (size_t)NBAT * NF * 4;
  float*  Dpart = (float*)w;               w += (size_t)NM * NDB * 4;
  float*  basep = (float*)Dpart;           // alias (read before k_gemm writes)
  float*  pb    = (float*)Dpart;           // alias (written after k_invd reads)
  float*  invD  = (float*)w;               w += (size_t)NM * 4;
  int*    rowmap= (int*)w;                 w += (size_t)NM * 4;
  int*    bcnt  = (int*)w;                 w += 128;
  int*    boff  = (int*)w;                 w += 128;
  int*    meta  = (int*)w;                 w += 128;

  (void)in_sizes; (void)n_in; (void)out_size; (void)ws_size;

  k_prep  <<<dim3(1), 256, 0, stream>>>(mask, bcnt, boff, meta);
  k_gather<<<dim3(NBAT), 512, 0, stream>>>(mask, boff, meta, rowmap);
  k_sum_h <<<dim3(NBAT, KH / 256), 256, 0, stream>>>(h_state, s);
  k_cvt_a <<<dim3(2048), 256, 0, stream>>>(h_state, x, rowmap, meta, Abf);
  k_wat   <<<dim3(NF / 64, NF / 64), 256, 0, stream>>>(Wa, WaT);
  k_base1 <<<dim3(NF / 256, KC), 256, 0, stream>>>(s, Ws, basep);
  k_base2 <<<dim3(NBAT, NF / 256), 256, 0, stream>>>(basep, ba, bs, base);
  k_gemm  <<<dim3((NF / 256) * (NM / 256)), 512, 0, stream>>>(Abf, WaT, base, rowmap, meta, P, Dpart);
  k_invd  <<<dim3(NM / 256), 256, 0, stream>>>(Dpart, meta, invD);
  k_final1<<<dim3(NBAT * NCH, NF / 512), 256, 0, stream>>>(P, invD, boff, bcnt, pb);
  k_final2<<<dim3(NBAT, NF / 256), 256, 0, stream>>>(pb, bcnt, h_state, x, trigger, out);
}